// Round 1
// baseline (1225.133 us; speedup 1.0000x reference)
//
#include <hip/hip_runtime.h>
#include <math.h>

#define S    256
#define Hp   288
#define C    32
#define KY   12
#define NK   24
#define Bn   8
#define PI_D 3.14159265358979323846264338327950288

// workspace offsets (in floats)
#define SZ_TW (NK*Hp*2)                 // 13824
#define OFF_TW 0
#define OFF_H  (OFF_TW + SZ_TW)
#define SZ_H   (Bn*C*Hp*Hp)             // 21233664
#define OFF_Y  (OFF_H + SZ_H)
#define SZ_Y   (Bn*C*Hp*KY*2)           // 1769472
#define OFF_X  (OFF_Y + SZ_Y)
#define SZ_X   (Bn*C*NK*KY*2)           // 147456
#define OFF_O  (OFF_X + SZ_X)
#define SZ_O   SZ_X
#define OFF_Z  (OFF_O + SZ_O)
#define SZ_Z   (Bn*Hp*C*KY*2)           // 1769472
#define OFF_T  (OFF_Z + SZ_Z)
#define SZ_T   (Bn*S*S*2)               // 1048576

// twiddle table: tw[k][x] = (cos, sin) of 2*pi*f(k)*x/288, f(k)= k<12 ? k : k+264
__global__ void k_tw(float* __restrict__ tw) {
    int i = blockIdx.x * 256 + threadIdx.x;
    if (i >= NK * Hp) return;
    int k = i / Hp, xx = i % Hp;
    int f = (k < KY) ? k : (k + 264);            // 276..287 = negative freqs -12..-1
    int m = (f * xx) % Hp;                        // exact integer phase reduction
    double th = (2.0 * PI_D * (double)m) / (double)Hp;
    tw[2 * i]     = (float)cos(th);
    tw[2 * i + 1] = (float)sin(th);
}

// gather + grid + fc0 + pad  ->  h[b][c][x][y] (288x288, zero pad region)
__global__ void k_embed(const float* __restrict__ xin, const int* __restrict__ d2v,
                        const float* __restrict__ fw, const float* __restrict__ fb,
                        float* __restrict__ h) {
    int id = blockIdx.x * 256 + threadIdx.x;      // Bn*Hp*Hp threads exactly
    int y = id % Hp; int t = id / Hp; int xr = t % Hp; int b = t / Hp;
    bool in = (xr < S) && (y < S);
    float xg = 0.f, gx = 0.f, gy = 0.f;
    if (in) {
        int p = xr * S + y;
        xg = xin[b * (S * S) + d2v[p]];
        gx = xr * (1.0f / 255.0f);
        gy = y  * (1.0f / 255.0f);
    }
    float* hb = h + (size_t)b * C * Hp * Hp + (size_t)xr * Hp + y;
    #pragma unroll
    for (int c = 0; c < C; ++c) {
        float v = in ? (fw[c * 3] * xg + fw[c * 3 + 1] * gx + fw[c * 3 + 2] * gy + fb[c]) : 0.0f;
        hb[(size_t)c * Hp * Hp] = v;
    }
}

// forward DFT along y: Y[b][c][x][ky] = sum_y h * e^{-2pi i ky y/288}, ky=0..11
__global__ __launch_bounds__(384) void k_dfty(const float* __restrict__ h,
                                              const float* __restrict__ tw,
                                              float* __restrict__ Y) {
    __shared__ float hs[32 * 289];
    int x0 = blockIdx.x * 32;
    int c = blockIdx.y, b = blockIdx.z;
    const float* hb = h + (((size_t)(b * C + c)) * Hp + x0) * Hp;
    for (int i = threadIdx.x; i < 32 * Hp; i += 384) {
        int r = i / Hp, yy = i % Hp;
        hs[r * 289 + yy] = hb[r * Hp + yy];
    }
    __syncthreads();
    int row = threadIdx.x & 31, ky = threadIdx.x >> 5;  // ky 0..11
    const float* twk = tw + ky * Hp * 2;
    const float* hr = hs + row * 289;
    float re = 0.f, im = 0.f;
    for (int yy = 0; yy < Hp; ++yy) {
        float v = hr[yy];
        re += v * twk[2 * yy];
        im -= v * twk[2 * yy + 1];
    }
    size_t o = ((((size_t)(b * C + c)) * Hp + x0 + row) * KY + ky) * 2;
    Y[o] = re; Y[o + 1] = im;
}

// forward DFT along x (24 retained modes): X[b][c][k][ky]
__global__ void k_dftx(const float* __restrict__ Y, const float* __restrict__ tw,
                       float* __restrict__ X) {
    int c = blockIdx.x, b = blockIdx.y;
    const float* Yb = Y + ((size_t)(b * C + c)) * Hp * KY * 2;
    for (int oi = threadIdx.x; oi < NK * KY; oi += 256) {
        int k = oi / KY, ky = oi % KY;
        const float* twk = tw + k * Hp * 2;
        float xr = 0.f, xi = 0.f;
        for (int xx = 0; xx < Hp; ++xx) {
            float yr = Yb[(xx * KY + ky) * 2], yi = Yb[(xx * KY + ky) * 2 + 1];
            float cc = twk[2 * xx], ss = twk[2 * xx + 1];
            xr += yr * cc + yi * ss;      // e^{-i t}
            xi += yi * cc - yr * ss;
        }
        size_t o = (((size_t)(b * C + c)) * NK * KY + oi) * 2;
        X[o] = xr; X[o + 1] = xi;
    }
}

// complex channel mix: O[b][o][k][ky] = sum_i X[b][i][k][ky] * W_l[i][o][k][ky]
__global__ void k_spec(const float* __restrict__ X,
                       const float* __restrict__ w1r, const float* __restrict__ w1i,
                       const float* __restrict__ w2r, const float* __restrict__ w2i,
                       float* __restrict__ O, int l) {
    int t = blockIdx.x * 256 + threadIdx.x;       // Bn*C*NK*KY exactly
    int ky = t % KY; int k = (t / KY) % NK; int o = (t / (NK * KY)) % C; int b = t / (C * NK * KY);
    int kk = (k < KY) ? k : (k - KY);
    const float* wr = (k < KY) ? w1r : w2r;
    const float* wi = (k < KY) ? w1i : w2i;
    size_t wbase = (size_t)l * C * C * 144 + (size_t)o * 144 + kk * 12 + ky;
    size_t xbase = (size_t)b * C * NK * KY * 2 + (k * KY + ky) * 2;
    float ar = 0.f, ai = 0.f;
    #pragma unroll 8
    for (int i = 0; i < C; ++i) {
        float xr = X[xbase + (size_t)i * NK * KY * 2];
        float xi = X[xbase + (size_t)i * NK * KY * 2 + 1];
        float wrr = wr[wbase + (size_t)i * C * 144];
        float wii = wi[wbase + (size_t)i * C * 144];
        ar += xr * wrr - xi * wii;
        ai += xr * wii + xi * wrr;
    }
    size_t oo = (((size_t)b * C + o) * NK * KY + k * KY + ky) * 2;
    O[oo] = ar; O[oo + 1] = ai;
}

// inverse DFT along x: Z[b][x][c][ky] = sum_k O * e^{+2pi i f(k) x /288}
__global__ __launch_bounds__(384) void k_idftx(const float* __restrict__ O,
                                               const float* __restrict__ tw,
                                               float* __restrict__ Z) {
    int x0 = blockIdx.x * 32; int c = blockIdx.y, b = blockIdx.z;
    int row = threadIdx.x & 31, ky = threadIdx.x >> 5;
    int x = x0 + row;
    const float* Ob = O + ((size_t)(b * C + c)) * NK * KY * 2 + ky * 2;
    float zr = 0.f, zi = 0.f;
    #pragma unroll
    for (int k = 0; k < NK; ++k) {
        float orr = Ob[k * KY * 2], oii = Ob[k * KY * 2 + 1];
        float cc = tw[(k * Hp + x) * 2], ss = tw[(k * Hp + x) * 2 + 1];
        zr += orr * cc - oii * ss;        // e^{+i t}
        zi += orr * ss + oii * cc;
    }
    size_t o = ((((size_t)b * Hp + x) * C + c) * KY + ky) * 2;
    Z[o] = zr; Z[o + 1] = zi;
}

// fused: 1x1 conv (LDS) + inverse DFT-y (Hermitian, Im(ky=0) dropped) + bias + gelu, in place
__global__ __launch_bounds__(256) void k_conv(float* __restrict__ h, const float* __restrict__ Z,
                                              const float* __restrict__ cw, const float* __restrict__ cb,
                                              const float* __restrict__ tw, int l, int do_gelu) {
    __shared__ float hs[32 * 289];
    __shared__ float zz[32 * 24];
    __shared__ float cws[32 * 33];
    __shared__ float cbs[32];
    int x = blockIdx.x, b = blockIdx.y;
    float* hb = h + (size_t)b * C * Hp * Hp + (size_t)x * Hp;   // element (c,y) at hb[c*82944+y]
    for (int i = threadIdx.x; i < 32 * Hp; i += 256) {
        int c = i / Hp, yy = i % Hp;
        hs[c * 289 + yy] = hb[c * 82944 + yy];
    }
    for (int i = threadIdx.x; i < 32 * 24; i += 256)
        zz[i] = Z[((size_t)(b * Hp + x)) * C * KY * 2 + i];
    for (int i = threadIdx.x; i < 32 * 32; i += 256)
        cws[(i / 32) * 33 + (i % 32)] = cw[l * 1024 + i];
    if (threadIdx.x < 32) cbs[threadIdx.x] = cb[l * 32 + threadIdx.x];
    __syncthreads();

    int o = threadIdx.x >> 3;
    int y0 = threadIdx.x & 7;
    for (int j = 0; j < 36; ++j) {
        int y = y0 + 8 * j;
        float s = cbs[o];
        #pragma unroll
        for (int c = 0; c < 32; ++c) s += hs[c * 289 + y] * cws[o * 33 + c];
        float sp = zz[o * 24];                        // ky=0: real part only
        #pragma unroll
        for (int ky = 1; ky < 12; ++ky) {
            float cc = tw[(ky * Hp + y) * 2], ss = tw[(ky * Hp + y) * 2 + 1];
            sp += 2.0f * (zz[o * 24 + 2 * ky] * cc - zz[o * 24 + 2 * ky + 1] * ss);
        }
        float val = s + sp * (1.0f / 82944.0f);       // 1/288 (ifft-x) * 1/288 (irfft-y)
        if (do_gelu) val = 0.5f * val * (1.0f + erff(val * 0.70710678118654752f));
        hb[o * 82944 + y] = val;
    }
}

// per-pixel MLP 32 -> gelu(128) -> 2, crop to 256x256, write tmp[b][p][d]
__global__ __launch_bounds__(256, 2) void k_mlp(const float* __restrict__ h,
                                                const float* __restrict__ w1, const float* __restrict__ b1,
                                                const float* __restrict__ w2, const float* __restrict__ b2,
                                                float* __restrict__ tmp) {
    int bid = blockIdx.x;                          // 512 blocks
    int b = bid >> 6;
    int x = ((bid & 63) << 2) + (threadIdx.x >> 6);
    int lane = threadIdx.x & 63;
    const float* hb = h + (size_t)b * C * Hp * Hp + (size_t)x * Hp;
    float hc[4][32];
    #pragma unroll
    for (int c = 0; c < 32; ++c) {
        #pragma unroll
        for (int k = 0; k < 4; ++k) hc[k][c] = hb[c * 82944 + lane + 64 * k];
    }
    float o0[4] = {0.f, 0.f, 0.f, 0.f}, o1[4] = {0.f, 0.f, 0.f, 0.f};
    for (int f = 0; f < 128; ++f) {
        float bb = b1[f];
        float a[4] = {bb, bb, bb, bb};
        #pragma unroll
        for (int c = 0; c < 32; ++c) {
            float w = w1[f * 32 + c];
            #pragma unroll
            for (int k = 0; k < 4; ++k) a[k] += hc[k][c] * w;
        }
        float wa = w2[f], wb = w2[128 + f];
        #pragma unroll
        for (int k = 0; k < 4; ++k) {
            float tt = 0.5f * a[k] * (1.0f + erff(a[k] * 0.70710678118654752f));
            o0[k] += tt * wa; o1[k] += tt * wb;
        }
    }
    #pragma unroll
    for (int k = 0; k < 4; ++k) {
        int y = lane + 64 * k;
        int p = x * S + y;
        size_t o = ((size_t)b * S * S + p) * 2;
        tmp[o]     = o0[k] + b2[0];
        tmp[o + 1] = o1[k] + b2[1];
    }
}

// out[b][j][d] = tmp[b][v2d[j]][d]
__global__ void k_scatter(const float* __restrict__ tmp, const int* __restrict__ v2d,
                          float* __restrict__ out) {
    int id = blockIdx.x * 256 + threadIdx.x;       // Bn*S*S exactly
    int b = id >> 16; int j = id & 65535;
    int p = v2d[j];
    const float2 v = *(const float2*)(tmp + ((size_t)(b << 16) + p) * 2);
    *(float2*)(out + (size_t)id * 2) = v;
}

extern "C" void kernel_launch(void* const* d_in, const int* in_sizes, int n_in,
                              void* d_out, int out_size, void* d_ws, size_t ws_size,
                              hipStream_t stream) {
    const float* xin   = (const float*)d_in[0];
    const int*   d2v   = (const int*)  d_in[1];
    const int*   v2d   = (const int*)  d_in[2];
    const float* fc0w  = (const float*)d_in[3];
    const float* fc0b  = (const float*)d_in[4];
    const float* w1r   = (const float*)d_in[5];
    const float* w1i   = (const float*)d_in[6];
    const float* w2r   = (const float*)d_in[7];
    const float* w2i   = (const float*)d_in[8];
    const float* cw    = (const float*)d_in[9];
    const float* cb    = (const float*)d_in[10];
    const float* mw1   = (const float*)d_in[11];
    const float* mb1   = (const float*)d_in[12];
    const float* mw2   = (const float*)d_in[13];
    const float* mb2   = (const float*)d_in[14];

    float* ws = (float*)d_ws;
    float* TW = ws + OFF_TW;
    float* H  = ws + OFF_H;
    float* Y  = ws + OFF_Y;
    float* X  = ws + OFF_X;
    float* O  = ws + OFF_O;
    float* Z  = ws + OFF_Z;
    float* T  = ws + OFF_T;

    k_tw<<<(NK * Hp + 255) / 256, 256, 0, stream>>>(TW);
    k_embed<<<(Bn * Hp * Hp) / 256, 256, 0, stream>>>(xin, d2v, fc0w, fc0b, H);

    for (int l = 0; l < 4; ++l) {
        k_dfty<<<dim3(9, 32, Bn), 384, 0, stream>>>(H, TW, Y);
        k_dftx<<<dim3(32, Bn), 256, 0, stream>>>(Y, TW, X);
        k_spec<<<(Bn * C * NK * KY) / 256, 256, 0, stream>>>(X, w1r, w1i, w2r, w2i, O, l);
        k_idftx<<<dim3(9, 32, Bn), 384, 0, stream>>>(O, TW, Z);
        k_conv<<<dim3(Hp, Bn), 256, 0, stream>>>(H, Z, cw, cb, TW, l, (l != 3) ? 1 : 0);
    }

    k_mlp<<<512, 256, 0, stream>>>(H, mw1, mb1, mw2, mb2, T);
    k_scatter<<<(Bn * S * S) / 256, 256, 0, stream>>>(T, v2d, (float*)d_out);
}